// Round 1
// baseline (1623.773 us; speedup 1.0000x reference)
//
#include <hip/hip_runtime.h>
#include <math.h>

// Problem constants
#define BB 4
#define TT 8
#define CC 128
#define HWW 9216            // 96*96
#define NH 4
#define HD 32
#define NPG 1179648.0f      // C*H*W elements per (b,t) group
#define EPS 1e-5f
#define SCALE 0.17677669529663687f   // 1/sqrt(32)

// ws layout in floats:
//  [0..64)        : sums[32][2]  (sum, sumsq)   -- zeroed via hipMemsetAsync
//  [64..4160)     : A[32][128]   xn = x*A + Bc
//  [4160..8256)   : Bc[32][128]
//  [8256..73792)  : M[4][128][128]   M[n][c][c2] = sum_d Wq_n[d,c]*Wk_n[d,c2]
//  [73792..139328): G[4][128][128]   G[n][e][c]  = sum_d P[e,n*32+d]*Wv_n[d,c]
#define WS_SUMS 0
#define WS_A    64
#define WS_B    4160
#define WS_M    8256
#define WS_G    73792

__global__ __launch_bounds__(256) void stats_kernel(
    const float* __restrict__ x, const float* __restrict__ pe,
    float* __restrict__ sums)
{
    const int g    = blockIdx.y;   // 32 groups (b*8+t)
    const int part = blockIdx.x;   // 16 parts, 8 channel-rows each
    const int tid  = threadIdx.x;
    const int t    = g & 7;
    float s1 = 0.f, s2 = 0.f;
    for (int r = 0; r < 8; ++r) {
        const int c = part * 8 + r;
        const float pec = pe[t * CC + c];
        const float4* row = (const float4*)(x + ((size_t)g * CC + c) * HWW);
        for (int i = tid; i < HWW / 4; i += 256) {
            float4 v = row[i];
            float a = v.x + pec, b = v.y + pec, cc2 = v.z + pec, d = v.w + pec;
            s1 += (a + b) + (cc2 + d);
            s2 += (a * a + b * b) + (cc2 * cc2 + d * d);
        }
    }
    for (int off = 32; off; off >>= 1) {
        s1 += __shfl_down(s1, off);
        s2 += __shfl_down(s2, off);
    }
    __shared__ float red[8];
    const int wid = tid >> 6, lane = tid & 63;
    if (lane == 0) { red[wid] = s1; red[4 + wid] = s2; }
    __syncthreads();
    if (tid == 0) {
        atomicAdd(&sums[g * 2 + 0], red[0] + red[1] + red[2] + red[3]);
        atomicAdd(&sums[g * 2 + 1], red[4] + red[5] + red[6] + red[7]);
    }
}

__global__ void finalize_kernel(
    const float* __restrict__ pe, const float* __restrict__ nw,
    const float* __restrict__ nb, float* ws)
{
    const int g = blockIdx.x;     // 32
    const int c = threadIdx.x;    // 128
    const float inv = 1.0f / NPG;
    const float mean = ws[WS_SUMS + g * 2 + 0] * inv;
    const float var  = ws[WS_SUMS + g * 2 + 1] * inv - mean * mean;
    const float rstd = rsqrtf(var + EPS);
    const int t = g & 7;
    const float a = rstd * nw[c];
    ws[WS_A + g * CC + c] = a;
    ws[WS_B + g * CC + c] = (pe[t * CC + c] - mean) * a + nb[c];
}

__global__ __launch_bounds__(256) void precompute_kernel(
    const float* __restrict__ qkv_w, const float* __restrict__ proj_w,
    float* __restrict__ ws)
{
    const int id = blockIdx.x * 256 + threadIdx.x;  // 131072 threads
    const int half = id >> 16;
    const int j = id & 65535;
    const int n = j >> 14, rem = j & 16383, a = rem >> 7, c = rem & 127;
    float s = 0.f;
    if (half == 0) {
        // M[n][a=c][c2=c]: sum_d qkv_w[n*32+d, a] * qkv_w[128+n*32+d, c]
        #pragma unroll
        for (int d = 0; d < HD; ++d)
            s += qkv_w[(n * HD + d) * CC + a] * qkv_w[(CC + n * HD + d) * CC + c];
        ws[WS_M + j] = s;
    } else {
        // G[n][e=a][c]: sum_d proj_w[a, n*32+d] * qkv_w[256+n*32+d, c]
        #pragma unroll
        for (int d = 0; d < HD; ++d)
            s += proj_w[a * CC + n * HD + d] * qkv_w[(2 * CC + n * HD + d) * CC + c];
        ws[WS_G + j] = s;
    }
}

#define TILE_P 64

__global__ __launch_bounds__(256) void main_kernel(
    const float* __restrict__ x, const float* __restrict__ ws,
    float* __restrict__ out)
{
    __shared__ float xn[CC][TILE_P];   // 32 KB
    __shared__ float yt[CC][TILE_P];   // 32 KB

    const int tid  = threadIdx.x;
    const int lane = tid & 63;
    const int p16  = tid & 15;        // quad within row for vector loads
    const int c16  = tid >> 4;        // row group for vector loads
    const int b    = blockIdx.y;
    const int hw0  = blockIdx.x * TILE_P;
    const int n    = __builtin_amdgcn_readfirstlane(tid >> 6);  // head = wave id

    const float* Mn = ws + WS_M + n * (CC * CC);
    const float* Gn = ws + WS_G + n * (CC * CC);

    // zero output accumulator tile
    for (int i = tid; i < CC * TILE_P; i += 256) ((float*)yt)[i] = 0.f;

    // cooperative tile load: xn[c][p] for time t (normalized)
    auto load_tile = [&](int t) {
        const int g = b * TT + t;
        const float* Ac = ws + WS_A + g * CC;
        const float* Bc = ws + WS_B + g * CC;
        const size_t base = ((size_t)g * CC) * HWW + hw0;
        #pragma unroll
        for (int i = 0; i < 8; ++i) {
            const int c = c16 + i * 16;
            float4 v = *(const float4*)(x + base + (size_t)c * HWW + p16 * 4);
            const float a = Ac[c], bb = Bc[c];
            float4 r;
            r.x = fmaf(v.x, a, bb); r.y = fmaf(v.y, a, bb);
            r.z = fmaf(v.z, a, bb); r.w = fmaf(v.w, a, bb);
            *(float4*)&xn[c][p16 * 4] = r;
        }
    };

    float acc[CC];
    #pragma unroll
    for (int i = 0; i < CC; ++i) acc[i] = 0.f;

    // ---- phase 0: load xn at t=7 ----
    load_tile(7);
    __syncthreads();

    // ---- phase 1: r[c2] = sum_c M_n[c][c2] * xn7[c]  (per (n,p) thread) ----
    for (int c = 0; c < CC; ++c) {
        const float xv = xn[c][lane];
        const float* Mrow = Mn + c * CC;
        #pragma unroll
        for (int j = 0; j < CC; ++j) acc[j] = fmaf(Mrow[j], xv, acc[j]);
    }

    // ---- phase 2: scores sc[t] = sum_c r[c]*xn_t[c] ----
    float sc[TT];
    for (int t = 0; t < TT; ++t) {
        __syncthreads();           // everyone done reading xn
        load_tile(t);
        __syncthreads();
        float s0 = 0.f, s1 = 0.f, s2 = 0.f, s3 = 0.f;
        #pragma unroll
        for (int c = 0; c < CC; c += 4) {
            s0 = fmaf(acc[c + 0], xn[c + 0][lane], s0);
            s1 = fmaf(acc[c + 1], xn[c + 1][lane], s1);
            s2 = fmaf(acc[c + 2], xn[c + 2][lane], s2);
            s3 = fmaf(acc[c + 3], xn[c + 3][lane], s3);
        }
        sc[t] = (s0 + s1) + (s2 + s3);
    }

    // ---- phase 3: softmax over t (scale applied) ----
    float m = sc[0];
    #pragma unroll
    for (int t = 1; t < TT; ++t) m = fmaxf(m, sc[t]);
    float wgt[TT];
    float wsum = 0.f;
    #pragma unroll
    for (int t = 0; t < TT; ++t) { wgt[t] = __expf((sc[t] - m) * SCALE); wsum += wgt[t]; }
    const float rws = 1.0f / wsum;
    #pragma unroll
    for (int t = 0; t < TT; ++t) wgt[t] *= rws;

    // ---- phase 4: xbar[c] = sum_t wgt[t]*xn_t[c]  (reuse acc regs) ----
    #pragma unroll
    for (int i = 0; i < CC; ++i) acc[i] = 0.f;
    for (int t = 0; t < TT; ++t) {
        __syncthreads();
        load_tile(t);
        __syncthreads();
        const float wt = wgt[t];
        #pragma unroll
        for (int c = 0; c < CC; ++c) acc[c] = fmaf(wt, xn[c][lane], acc[c]);
    }

    // ---- phase 5: y[e] += sum_c G_n[e][c]*xbar[c], rotated e-slices (no atomics) ----
    for (int round = 0; round < 4; ++round) {
        __syncthreads();
        const int e0 = (((n + round) & 3) * 32);
        for (int e = e0; e < e0 + 32; ++e) {
            const float* Grow = Gn + e * CC;
            float y0 = 0.f, y1 = 0.f, y2 = 0.f, y3 = 0.f;
            #pragma unroll
            for (int c = 0; c < CC; c += 4) {
                y0 = fmaf(Grow[c + 0], acc[c + 0], y0);
                y1 = fmaf(Grow[c + 1], acc[c + 1], y1);
                y2 = fmaf(Grow[c + 2], acc[c + 2], y2);
                y3 = fmaf(Grow[c + 3], acc[c + 3], y3);
            }
            yt[e][lane] += (y0 + y1) + (y2 + y3);
        }
    }

    // ---- write out: out[b][e][hw0+p] ----
    __syncthreads();
    for (int i = tid; i < CC * TILE_P; i += 256) {
        const int e = i >> 6, p = i & 63;
        out[((size_t)b * CC + e) * HWW + hw0 + p] = yt[e][p];
    }
}

extern "C" void kernel_launch(void* const* d_in, const int* in_sizes, int n_in,
                              void* d_out, int out_size, void* d_ws, size_t ws_size,
                              hipStream_t stream) {
    const float* x      = (const float*)d_in[0];
    const float* pe     = (const float*)d_in[1];
    const float* nw     = (const float*)d_in[2];
    const float* nb     = (const float*)d_in[3];
    const float* qkv_w  = (const float*)d_in[4];
    const float* proj_w = (const float*)d_in[5];
    float* out = (float*)d_out;
    float* ws  = (float*)d_ws;

    hipMemsetAsync(ws, 0, 64 * sizeof(float), stream);
    stats_kernel<<<dim3(16, 32), 256, 0, stream>>>(x, pe, ws);
    finalize_kernel<<<32, 128, 0, stream>>>(pe, nw, nb, ws);
    precompute_kernel<<<512, 256, 0, stream>>>(qkv_w, proj_w, ws);
    main_kernel<<<dim3(HWW / TILE_P, BB), 256, 0, stream>>>(x, ws, out);
}